// Round 2
// baseline (618.410 us; speedup 1.0000x reference)
//
#include <hip/hip_runtime.h>
#include <math.h>

// CRF LLH, B=512,S=512,C=96.  32 blocks x 128 thr; block owns 16 chains.
// wave0: recurrence TRANSPOSED into MFMA B-operand:
//   D[j][chain] = sum_k Et[j][k] * W[k][chain];  A = Et = exp(trans)^T fixed
//   in 18 half8 register fragments; state W lives ONLY in registers (B-frags).
//   D-layout -> B-layout relabel = 24 ds_bpermute (no LDS round trip, no bank
//   conflicts).  Per-chain power-of-2 rescale: pk_max tree on state + xor16/32
//   cross-lane, exponent extracted from fp16 bits, scale folded into the
//   exp(em) fp16 multiply; exact integer exponent debt sk accumulated.
// wave1: stages exp(em) fp16 rows + mask flags into a 16-slot LDS ring,
//   8 rows ahead, lgkm-only barrier every 4 steps; after the loop it computes
//   the numerator (tag-path gather) for the block's 16 chains.
// Verified-by-R1-pass layout facts reused: A/B frag k = 8*(lane>>4)+elem;
// C/D: col=lane&15, row=4*(lane>>4)+reg.

#define BATCH 512
#define SEQ   512
#define NC    96
#define CH    16
#define NBLK  (BATCH/CH)
#define NTHR  128
#define LN2   0.69314718055994531f

typedef __fp16 half2v __attribute__((ext_vector_type(2)));
typedef __fp16 half8  __attribute__((ext_vector_type(8)));
typedef float  f32x4  __attribute__((ext_vector_type(4)));
typedef unsigned int uint2v __attribute__((ext_vector_type(2)));
typedef unsigned int uint4v __attribute__((ext_vector_type(4)));

// lgkm-only barrier (keeps global prefetch in flight)
#define BARRIER() asm volatile("s_waitcnt lgkmcnt(0)\n\ts_barrier" ::: "memory")

#define DPP_STEP_F(v, op, ctrl)                                              \
    v = op(v, __int_as_float(__builtin_amdgcn_update_dpp(                    \
            __float_as_int(v), __float_as_int(v), (ctrl), 0xf, 0xf, false)))

__device__ __forceinline__ float fadd_(float a, float b) { return a + b; }
__device__ __forceinline__ float wave_sum_all(float v) {
    DPP_STEP_F(v, fadd_, 0x111);
    DPP_STEP_F(v, fadd_, 0x112);
    DPP_STEP_F(v, fadd_, 0x114);
    DPP_STEP_F(v, fadd_, 0x118);
    DPP_STEP_F(v, fadd_, 0x142);
    DPP_STEP_F(v, fadd_, 0x143);
    return __int_as_float(__builtin_amdgcn_readlane(__float_as_int(v), 63));
}

__device__ __forceinline__ unsigned pkmax(unsigned a, unsigned b) {
    unsigned d;
    asm("v_pk_max_f16 %0, %1, %2" : "=v"(d) : "v"(a), "v"(b));
    return d;
}
__device__ __forceinline__ unsigned pk2(float a, float b) {
    return __builtin_bit_cast(unsigned, __builtin_amdgcn_cvt_pkrtz(a, b));
}
__device__ __forceinline__ float dot8(half8 a, uint4v b, float c) {
    uint4v au = __builtin_bit_cast(uint4v, a);
    c = __builtin_amdgcn_fdot2(__builtin_bit_cast(half2v, au.x), __builtin_bit_cast(half2v, b.x), c, false);
    c = __builtin_amdgcn_fdot2(__builtin_bit_cast(half2v, au.y), __builtin_bit_cast(half2v, b.y), c, false);
    c = __builtin_amdgcn_fdot2(__builtin_bit_cast(half2v, au.z), __builtin_bit_cast(half2v, b.z), c, false);
    c = __builtin_amdgcn_fdot2(__builtin_bit_cast(half2v, au.w), __builtin_bit_cast(half2v, b.w), c, false);
    return c;
}

__global__ __launch_bounds__(NTHR, 1)
void crf_fused_kernel(const float* __restrict__ em,      // (B,S,C)
                      const int*   __restrict__ tags,    // (B,S)
                      const int*   __restrict__ masks,   // (B,S)
                      const float* __restrict__ startT,  // (C)
                      const float* __restrict__ endT,    // (C)
                      const float* __restrict__ trans,   // (C,C)
                      float*       __restrict__ out)     // scalar
{
    const int tid = threadIdx.x;
    const int l   = tid & 63;
    const int w   = tid >> 6;
    const int c0  = blockIdx.x * CH;

    __shared__ __align__(16) __fp16 EMR[16][CH * 104];   // exp(em) ring
    __shared__ __align__(8)  unsigned short FLG[16][CH]; // mask flags ring

    if (w == 0) {
        // ================= compute wave =================
        const int n = l & 15;       // chain (and D-col / A-row / B-col)
        const int g = l >> 4;       // 16-lane group
        const bool hi = (g >= 2);
        const int addrE = ((32 * (g & 1)) + n) << 2;
        const int addrO = addrE + (16 << 2);
        const int addrX32 = (l ^ 32) << 2;

        // A-fragments: Ea[r][c][e] = Et[16r+n][32c+8g+e] = exp(trans[k][j])
        half8 Ea[6][3];
        #pragma unroll
        for (int r = 0; r < 6; ++r)
            #pragma unroll
            for (int c = 0; c < 3; ++c) {
                half8 v;
                #pragma unroll
                for (int e2 = 0; e2 < 8; ++e2)
                    v[e2] = (__fp16)__expf(trans[(32 * c + 8 * g + e2) * NC + 16 * r + n]);
                Ea[r][c] = v;
            }

        BARRIER();   // staging prologue done: EMR slot 0 (row 0) valid

        // init state: Bw[c] holds w0[k=32c+8g+e][chain=n], w0 = e^start * e^em0
        uint4v Bw[3];
        #pragma unroll
        for (int c = 0; c < 3; ++c) {
            const float4 sa = *(const float4*)(startT + 32 * c + 8 * g);
            const float4 sb = *(const float4*)(startT + 32 * c + 8 * g + 4);
            const uint4v E0 = *(const uint4v*)(&EMR[0][n * 104 + 32 * c + 8 * g]);
            half2v q0 = __builtin_amdgcn_cvt_pkrtz(__expf(sa.x), __expf(sa.y)) * __builtin_bit_cast(half2v, E0.x);
            half2v q1 = __builtin_amdgcn_cvt_pkrtz(__expf(sa.z), __expf(sa.w)) * __builtin_bit_cast(half2v, E0.y);
            half2v q2 = __builtin_amdgcn_cvt_pkrtz(__expf(sb.x), __expf(sb.y)) * __builtin_bit_cast(half2v, E0.z);
            half2v q3 = __builtin_amdgcn_cvt_pkrtz(__expf(sb.z), __expf(sb.w)) * __builtin_bit_cast(half2v, E0.w);
            Bw[c].x = __builtin_bit_cast(unsigned, q0);
            Bw[c].y = __builtin_bit_cast(unsigned, q1);
            Bw[c].z = __builtin_bit_cast(unsigned, q2);
            Bw[c].w = __builtin_bit_cast(unsigned, q3);
        }

        int sk = 0;   // exact accumulated exponent debt (per chain, dup x4)

        #pragma unroll 1
        for (int s = 1; s < SEQ; ++s) {
            if ((s & 3) == 1) BARRIER();
            const int slot = s & 15;

            // issue em reads (D-layout j = 16r+4g+p) + flag; latency hides
            // under the MFMA phase (MFMA depends only on registers).
            const __fp16* emrow = &EMR[slot][n * 104 + 4 * g];
            uint2v emv[6];
            #pragma unroll
            for (int r = 0; r < 6; ++r)
                emv[r] = *(const uint2v*)(emrow + 16 * r);
            const int flg = FLG[slot][n];

            // scale bookkeeping from CURRENT state (pre-update): fp16 pk_max
            // tree + xor16/xor32; exponent e of max -> scl = 2^{8-e}, shift=e-8
            unsigned t0 = pkmax(Bw[0].x, Bw[0].y), t1 = pkmax(Bw[0].z, Bw[0].w);
            unsigned t2 = pkmax(Bw[1].x, Bw[1].y), t3 = pkmax(Bw[1].z, Bw[1].w);
            unsigned t4 = pkmax(Bw[2].x, Bw[2].y), t5 = pkmax(Bw[2].z, Bw[2].w);
            t0 = pkmax(t0, t1); t2 = pkmax(t2, t3); t4 = pkmax(t4, t5);
            t0 = pkmax(t0, t2); t0 = pkmax(t0, t4);
            t0 = pkmax(t0, t0 >> 16);
            t0 = pkmax(t0, (unsigned)__builtin_amdgcn_ds_swizzle((int)t0, 0x401F));
            t0 = pkmax(t0, (unsigned)__builtin_amdgcn_ds_bpermute(addrX32, (int)t0));
            const unsigned eexp = (t0 >> 10) & 31u;
            const float sclf = __uint_as_float((135u - eexp) << 23);
            const half2v scl2 = __builtin_amdgcn_cvt_pkrtz(sclf, sclf);

            // MFMA: D[j][chain] = sum over 3 k-chunks; 6 independent chains
            f32x4 acc[6];
            const f32x4 z = {0.f, 0.f, 0.f, 0.f};
            #pragma unroll
            for (int r = 0; r < 6; ++r)
                acc[r] = __builtin_amdgcn_mfma_f32_16x16x32_f16(Ea[r][0], __builtin_bit_cast(half8, Bw[0]), z, 0, 0, 0);
            #pragma unroll
            for (int r = 0; r < 6; ++r)
                acc[r] = __builtin_amdgcn_mfma_f32_16x16x32_f16(Ea[r][1], __builtin_bit_cast(half8, Bw[1]), acc[r], 0, 0, 0);
            #pragma unroll
            for (int r = 0; r < 6; ++r)
                acc[r] = __builtin_amdgcn_mfma_f32_16x16x32_f16(Ea[r][2], __builtin_bit_cast(half8, Bw[2]), acc[r], 0, 0, 0);

            // pack raw u -> fp16, multiply by (e^em * scl): w-candidate, D-layout
            unsigned Pw[12];
            #pragma unroll
            for (int r = 0; r < 6; ++r) {
                half2v u01 = __builtin_amdgcn_cvt_pkrtz(acc[r][0], acc[r][1]);
                half2v u23 = __builtin_amdgcn_cvt_pkrtz(acc[r][2], acc[r][3]);
                u01 = u01 * (__builtin_bit_cast(half2v, emv[r].x) * scl2);
                u23 = u23 * (__builtin_bit_cast(half2v, emv[r].y) * scl2);
                Pw[2 * r]     = __builtin_bit_cast(unsigned, u01);
                Pw[2 * r + 1] = __builtin_bit_cast(unsigned, u23);
            }

            // D-layout -> B-layout relabel: 24 ds_bpermute + selects; then
            // mask gate (masked step keeps old state).
            #pragma unroll
            for (int c = 0; c < 3; ++c) {
                const int p0 = (int)Pw[4 * c],     p1 = (int)Pw[4 * c + 1];
                const int p2 = (int)Pw[4 * c + 2], p3 = (int)Pw[4 * c + 3];
                const unsigned a0 = (unsigned)__builtin_amdgcn_ds_bpermute(addrE, p0);
                const unsigned b0 = (unsigned)__builtin_amdgcn_ds_bpermute(addrE, p2);
                const unsigned a1 = (unsigned)__builtin_amdgcn_ds_bpermute(addrE, p1);
                const unsigned b1 = (unsigned)__builtin_amdgcn_ds_bpermute(addrE, p3);
                const unsigned a2 = (unsigned)__builtin_amdgcn_ds_bpermute(addrO, p0);
                const unsigned b2 = (unsigned)__builtin_amdgcn_ds_bpermute(addrO, p2);
                const unsigned a3 = (unsigned)__builtin_amdgcn_ds_bpermute(addrO, p1);
                const unsigned b3 = (unsigned)__builtin_amdgcn_ds_bpermute(addrO, p3);
                const unsigned u0 = hi ? b0 : a0;
                const unsigned u1 = hi ? b1 : a1;
                const unsigned u2 = hi ? b2 : a2;
                const unsigned u3 = hi ? b3 : a3;
                Bw[c].x = flg ? u0 : Bw[c].x;
                Bw[c].y = flg ? u1 : Bw[c].y;
                Bw[c].z = flg ? u2 : Bw[c].z;
                Bw[c].w = flg ? u3 : Bw[c].w;
            }
            sk += flg ? ((int)eexp - 8) : 0;
        }

        // ---- denominator: dv[chain] = sum_j w[j]*e^{end[j]}
        float dv = 0.f;
        #pragma unroll
        for (int c = 0; c < 3; ++c) {
            const float4 ea = *(const float4*)(endT + 32 * c + 8 * g);
            const float4 eb2 = *(const float4*)(endT + 32 * c + 8 * g + 4);
            uint4v ex;
            ex.x = pk2(__expf(ea.x), __expf(ea.y));
            ex.y = pk2(__expf(ea.z), __expf(ea.w));
            ex.z = pk2(__expf(eb2.x), __expf(eb2.y));
            ex.w = pk2(__expf(eb2.z), __expf(eb2.w));
            dv = dot8(__builtin_bit_cast(half8, Bw[c]), ex, dv);
        }
        dv += __int_as_float(__builtin_amdgcn_ds_swizzle(__float_as_int(dv), 0x401F));
        dv += __int_as_float(__builtin_amdgcn_ds_bpermute(addrX32, __float_as_int(dv)));
        const float den = (float)sk * LN2 + __logf(dv);
        float contrib = (l < 16) ? den : 0.f;
        contrib = wave_sum_all(contrib);
        if (l == 0) atomicAdd(out, -contrib * (1.0f / (float)BATCH));
    } else {
        // ================= staging wave (then numerator) =================
        const int q  = l;
        const int ch = q >> 2;
        const int cb = (q & 3) * 24;
        const float* emc  = em + (size_t)(c0 + ch) * SEQ * NC + cb;
        const int*   mrow = masks + (size_t)(c0 + ch) * SEQ;

#define STAGE6(SL, V0, V1, V2, V3, V4, V5, FV) do {                           \
        uint4v* _d = (uint4v*)(&EMR[(SL)][ch * 104 + cb]);                    \
        uint4v _w0 = { pk2(__expf((V0).x), __expf((V0).y)),                   \
                       pk2(__expf((V0).z), __expf((V0).w)),                   \
                       pk2(__expf((V1).x), __expf((V1).y)),                   \
                       pk2(__expf((V1).z), __expf((V1).w)) };                 \
        uint4v _w1 = { pk2(__expf((V2).x), __expf((V2).y)),                   \
                       pk2(__expf((V2).z), __expf((V2).w)),                   \
                       pk2(__expf((V3).x), __expf((V3).y)),                   \
                       pk2(__expf((V3).z), __expf((V3).w)) };                 \
        uint4v _w2 = { pk2(__expf((V4).x), __expf((V4).y)),                   \
                       pk2(__expf((V4).z), __expf((V4).w)),                   \
                       pk2(__expf((V5).x), __expf((V5).y)) };                 \
        _w2.w = pk2(__expf((V5).z), __expf((V5).w));                          \
        _d[0] = _w0; _d[1] = _w1; _d[2] = _w2;                                \
        if ((q & 3) == 0) FLG[(SL)][ch] = (unsigned short)(FV);               \
    } while (0)

#define LOAD6(E, V0, V1, V2, V3, V4, V5, FV) do {                             \
        const float* _p = emc + (size_t)(E) * NC;                             \
        V0 = *(const float4*)(_p + 0);  V1 = *(const float4*)(_p + 4);        \
        V2 = *(const float4*)(_p + 8);  V3 = *(const float4*)(_p + 12);       \
        V4 = *(const float4*)(_p + 16); V5 = *(const float4*)(_p + 20);       \
        FV = (mrow[(E)] != 0);                                                \
    } while (0)

        // prologue: stage rows 0..8
        for (int e = 0; e <= 8; ++e) {
            float4 v0, v1, v2, v3, v4, v5; int fv = 1;
            LOAD6(e, v0, v1, v2, v3, v4, v5, fv);
            STAGE6(e, v0, v1, v2, v3, v4, v5, fv);
        }
        float4 a0, a1, a2, a3, a4, a5, b0, b1, b2, b3, b4, b5;
        int fa = 1, fb = 1;
        LOAD6(9,  a0, a1, a2, a3, a4, a5, fa);
        LOAD6(10, b0, b1, b2, b3, b4, b5, fb);

        BARRIER();   // release compute wave (slot 0 ready)

        #pragma unroll 1
        for (int s = 1; s < SEQ; s += 2) {
            if ((s & 3) == 1) BARRIER();
            {
                const int e = s + 8;
                if (e < SEQ) STAGE6(e & 15, a0, a1, a2, a3, a4, a5, fa);
                const int e2 = s + 10;
                if (e2 < SEQ) LOAD6(e2, a0, a1, a2, a3, a4, a5, fa);
            }
            {
                const int e = s + 9;
                if (e < SEQ) STAGE6(e & 15, b0, b1, b2, b3, b4, b5, fb);
                const int e2 = s + 11;
                if (e2 < SEQ) LOAD6(e2, b0, b1, b2, b3, b4, b5, fb);
            }
        }
#undef STAGE6
#undef LOAD6

        // ---- numerator: tag-path gather, 4 lanes per chain x 128 steps
        const int q4 = l & 3;
        const int*   tb = tags  + (size_t)(c0 + ch) * SEQ;
        const float* eb = em    + (size_t)(c0 + ch) * SEQ * NC;
        float nsum = 0.f, msum = 0.f;
        #pragma unroll 4
        for (int kk = 0; kk < SEQ / 4; ++kk) {
            const int s  = q4 * (SEQ / 4) + kk;
            const int tg = tb[s];
            const int mk = mrow[s];
            msum += mk ? 1.f : 0.f;
            if (s == 0) {
                nsum += startT[tg] + eb[tg];
            } else if (mk) {
                nsum += trans[tb[s - 1] * NC + tg] + eb[(size_t)s * NC + tg];
            }
        }
        nsum += __int_as_float(__builtin_amdgcn_ds_swizzle(__float_as_int(nsum), 0x041F));
        nsum += __int_as_float(__builtin_amdgcn_ds_swizzle(__float_as_int(nsum), 0x081F));
        msum += __int_as_float(__builtin_amdgcn_ds_swizzle(__float_as_int(msum), 0x041F));
        msum += __int_as_float(__builtin_amdgcn_ds_swizzle(__float_as_int(msum), 0x081F));
        float contrib = 0.f;
        if (q4 == 0) {
            const int cnt  = (int)msum;
            const int last = tb[cnt - 1];
            contrib = nsum + endT[last];
        }
        contrib = wave_sum_all(contrib);
        if (l == 0) atomicAdd(out, contrib * (1.0f / (float)BATCH));
    }
}

extern "C" void kernel_launch(void* const* d_in, const int* in_sizes, int n_in,
                              void* d_out, int out_size, void* d_ws, size_t ws_size,
                              hipStream_t stream) {
    const float* em     = (const float*)d_in[0];
    const int*   tags   = (const int*)  d_in[1];
    const int*   masks  = (const int*)  d_in[2];
    const float* startT = (const float*)d_in[3];
    const float* endT   = (const float*)d_in[4];
    const float* trans  = (const float*)d_in[5];
    float* out = (float*)d_out;

    (void)hipMemsetAsync(out, 0, sizeof(float), stream);
    crf_fused_kernel<<<NBLK, NTHR, 0, stream>>>(em, tags, masks, startT, endT, trans, out);
}

// Round 3
// 426.314 us; speedup vs baseline: 1.4506x; 1.4506x over previous
//
#include <hip/hip_runtime.h>
#include <math.h>

// CRF LLH, B=512,S=512,C=96.  512 blocks x 256 thr (4 waves); block owns ONE
// chain.  Key idea: halve the serial chain by pairing steps.
//   pair t (steps 2t+1, 2t+2):  w <- (w . G_t) * diag(e^{em[2t+2]})
//   G_t = E . diag(e^{em[2t+1]}) . E   (state-independent!)
// wave0 (consumer): per pair, one 96x96 matvec via fdot2 (state broadcast in
//   LDS, G columns read from LDS), exact pow-2 rescale (DPP max + exponent),
//   integer exponent debt sk.  255 pairs + final single step (s=511) vs a
//   resident E copy.  Serial chain = 255 matvecs instead of 511.
// waves1-3 (producers): build G_{t+1} (36 MFMA 16x16x32_f16 each, 2 col-tiles
//   per wave) into the other LDS buffer while consumer eats G_t; d1 rows
//   prefetched distance-2 from global.  Barrier once per pair (255 each side).
// Masks: all-ones input takes the fast path; cold fallback does per-sub-step
//   matvecs against resident E.  Numerator: wave1 post-loop (tag gather).
// Layout facts (verified R1/R2 pass): A[m][k]: lane&15=m, e<->k=8*(lane>>4)+e
// (+32/c-frag); B[k][n]: lane&15=n, same k; D: col=lane&15, row=4*(lane>>4)+reg.

#define BATCH 512
#define SEQ   512
#define NC    96
#define NTHR  256
#define CSTR  120            // LDS column stride in halfs (bank-friendly, 16B-aligned)
#define GHALF (NC * CSTR)    // 11520 halfs per matrix
#define LN2   0.69314718055994531f

typedef __fp16 half2v __attribute__((ext_vector_type(2)));
typedef __fp16 half8  __attribute__((ext_vector_type(8)));
typedef float  f32x4  __attribute__((ext_vector_type(4)));
typedef unsigned int uint2v __attribute__((ext_vector_type(2)));
typedef unsigned int uint4v __attribute__((ext_vector_type(4)));

#define BARRIER() asm volatile("s_waitcnt lgkmcnt(0)\n\ts_barrier" ::: "memory")
#define LGKM0()   asm volatile("s_waitcnt lgkmcnt(0)" ::: "memory")

#define DPP_STEP_F(v, op, ctrl)                                              \
    v = op(v, __int_as_float(__builtin_amdgcn_update_dpp(                    \
            __float_as_int(v), __float_as_int(v), (ctrl), 0xf, 0xf, false)))

__device__ __forceinline__ float fadd_(float a, float b) { return a + b; }
__device__ __forceinline__ float wave_sum_all(float v) {
    DPP_STEP_F(v, fadd_, 0x111);
    DPP_STEP_F(v, fadd_, 0x112);
    DPP_STEP_F(v, fadd_, 0x114);
    DPP_STEP_F(v, fadd_, 0x118);
    DPP_STEP_F(v, fadd_, 0x142);
    DPP_STEP_F(v, fadd_, 0x143);
    return __int_as_float(__builtin_amdgcn_readlane(__float_as_int(v), 63));
}
__device__ __forceinline__ float wave_max_all(float v) {
    DPP_STEP_F(v, fmaxf, 0x111);
    DPP_STEP_F(v, fmaxf, 0x112);
    DPP_STEP_F(v, fmaxf, 0x114);
    DPP_STEP_F(v, fmaxf, 0x118);
    DPP_STEP_F(v, fmaxf, 0x142);
    DPP_STEP_F(v, fmaxf, 0x143);
    return __int_as_float(__builtin_amdgcn_readlane(__float_as_int(v), 63));
}

__device__ __forceinline__ unsigned bcu(half2v h) { return __builtin_bit_cast(unsigned, h); }
__device__ __forceinline__ half2v bch(unsigned u) { return __builtin_bit_cast(half2v, u); }
__device__ __forceinline__ float fdot2_(unsigned a, unsigned b, float c) {
    return __builtin_amdgcn_fdot2(bch(a), bch(b), c, false);
}

// matvec over two columns: u0 = sum_i st[i]*base[c0][i], u1 = same for c0+1
__device__ __forceinline__ void matvec96(const __fp16* base, const __fp16* st,
                                         int jj, float& u0, float& u1) {
    const uint4v* c0 = (const uint4v*)(base + (2 * jj) * CSTR);
    const uint4v* c1 = (const uint4v*)(base + (2 * jj) * CSTR + CSTR);
    const uint4v* sp = (const uint4v*)st;
    uint4v g0[12], g1[12], sv[12];
    #pragma unroll
    for (int q = 0; q < 12; ++q) g0[q] = c0[q];
    #pragma unroll
    for (int q = 0; q < 12; ++q) g1[q] = c1[q];
    #pragma unroll
    for (int q = 0; q < 12; ++q) sv[q] = sp[q];
    float a0 = 0.f, a1 = 0.f, a2 = 0.f, a3 = 0.f;
    float b0 = 0.f, b1 = 0.f, b2 = 0.f, b3 = 0.f;
    #pragma unroll
    for (int q = 0; q < 12; ++q) {
        a0 = fdot2_(sv[q].x, g0[q].x, a0);
        a1 = fdot2_(sv[q].y, g0[q].y, a1);
        a2 = fdot2_(sv[q].z, g0[q].z, a2);
        a3 = fdot2_(sv[q].w, g0[q].w, a3);
        b0 = fdot2_(sv[q].x, g1[q].x, b0);
        b1 = fdot2_(sv[q].y, g1[q].y, b1);
        b2 = fdot2_(sv[q].z, g1[q].z, b2);
        b3 = fdot2_(sv[q].w, g1[q].w, b3);
    }
    u0 = (a0 + a1) + (a2 + a3);
    u1 = (b0 + b1) + (b2 + b3);
}

struct PF { float4 a0, a1, b0, b1, c0, c1; };   // one em row, this lane's k-slices

__device__ __forceinline__ PF ld6(const float* p_base, int row, int g) {
    const float* p = p_base + (size_t)row * NC + 8 * g;
    PF x;
    x.a0 = *(const float4*)(p);      x.a1 = *(const float4*)(p + 4);
    x.b0 = *(const float4*)(p + 32); x.b1 = *(const float4*)(p + 36);
    x.c0 = *(const float4*)(p + 64); x.c1 = *(const float4*)(p + 68);
    return x;
}

__device__ __forceinline__ half8 exp8(float4 u, float4 v) {
    uint4v r;
    r.x = bcu(__builtin_amdgcn_cvt_pkrtz(__expf(u.x), __expf(u.y)));
    r.y = bcu(__builtin_amdgcn_cvt_pkrtz(__expf(u.z), __expf(u.w)));
    r.z = bcu(__builtin_amdgcn_cvt_pkrtz(__expf(v.x), __expf(v.y)));
    r.w = bcu(__builtin_amdgcn_cvt_pkrtz(__expf(v.z), __expf(v.w)));
    return __builtin_bit_cast(half8, r);
}

__global__ __launch_bounds__(NTHR, 2)
void crf_pair_kernel(const float* __restrict__ em,      // (B,S,C)
                     const int*   __restrict__ tags,    // (B,S)
                     const int*   __restrict__ masks,   // (B,S)
                     const float* __restrict__ startT,  // (C)
                     const float* __restrict__ endT,    // (C)
                     const float* __restrict__ trans,   // (C,C)
                     float*       __restrict__ out)     // scalar
{
    const int tid = threadIdx.x;
    const int l   = tid & 63;
    const int w   = tid >> 6;
    const int b   = blockIdx.x;

    __shared__ __align__(16) __fp16 GB[2][GHALF];   // pair-matrix double buffer
    __shared__ __align__(16) __fp16 EB[GHALF];      // resident E (col-major)
    __shared__ __align__(16) __fp16 ST[128];        // state w (96 halfs)

    const float* em_b    = em    + (size_t)b * SEQ * NC;
    const int*   masks_b = masks + (size_t)b * SEQ;

    if (w == 0) {
        // ===================== consumer =====================
        const int jj = (l < 48) ? l : (l - 48);

        const float2 st2 = *(const float2*)(startT + 2 * jj);
        const float2 e00 = *(const float2*)(em_b + 2 * jj);
        const float al0 = st2.x + e00.x, al1 = st2.y + e00.y;
        const float M0 = wave_max_all(fmaxf(al0, al1));
        if (l < 48)
            ((unsigned*)ST)[jj] = bcu(__builtin_amdgcn_cvt_pkrtz(
                __expf(al0 - M0), __expf(al1 - M0)));
        int sk = 0;

        float2 e2A = *(const float2*)(em_b + (size_t)2 * NC + 2 * jj);
        float2 e2B = *(const float2*)(em_b + (size_t)4 * NC + 2 * jj);
        int mkA = (masks_b[1] ? 1 : 0) | (masks_b[2] ? 2 : 0);
        int mkB = (masks_b[3] ? 1 : 0) | (masks_b[4] ? 2 : 0);

        auto sstep = [&](int row) {     // cold path: one exact single step vs E
            LGKM0();
            float v0, v1;
            matvec96(EB, ST, jj, v0, v1);
            const float2 ee = *(const float2*)(em_b + (size_t)row * NC + 2 * jj);
            v0 *= __expf(ee.x); v1 *= __expf(ee.y);
            const float mx = wave_max_all(fmaxf(v0, v1));
            const unsigned ebx = (__float_as_uint(mx) >> 23) & 255u;
            sk += (int)ebx - 127;
            const float sc = __uint_as_float((254u - ebx) << 23);
            if (l < 48)
                ((unsigned*)ST)[jj] = bcu(__builtin_amdgcn_cvt_pkrtz(v0 * sc, v1 * sc));
            LGKM0();
        };

        auto body = [&](int t, float2 e2, int mk) {
            BARRIER();                      // G[t] ready in GB[t&1]
            float u0, u1;
            matvec96(&GB[t & 1][0], ST, jj, u0, u1);
            if (mk == 3) {
                u0 *= __expf(e2.x); u1 *= __expf(e2.y);
                const float mx = wave_max_all(fmaxf(u0, u1));
                const unsigned ebx = (__float_as_uint(mx) >> 23) & 255u;
                sk += (int)ebx - 127;
                const float sc = __uint_as_float((254u - ebx) << 23);
                if (l < 48)
                    ((unsigned*)ST)[jj] = bcu(__builtin_amdgcn_cvt_pkrtz(u0 * sc, u1 * sc));
            } else {                        // never taken for all-ones masks
                if (mk & 1) sstep(2 * t + 1);
                if (mk & 2) sstep(2 * t + 2);
            }
        };

        #pragma unroll 1
        for (int t = 0; t < 254; t += 2) {
            body(t, e2A, mkA);
            {
                const int rb = 2 * t + 6;   // <= 510
                e2A = *(const float2*)(em_b + (size_t)rb * NC + 2 * jj);
                mkA = (masks_b[2 * t + 5] ? 1 : 0) | (masks_b[rb] ? 2 : 0);
            }
            body(t + 1, e2B, mkB);
            {
                const int ra = 2 * t + 7;               // <= 511
                const int rb = (2 * t + 8 > 511) ? 511 : (2 * t + 8);
                e2B = *(const float2*)(em_b + (size_t)rb * NC + 2 * jj);
                mkB = (masks_b[ra] ? 1 : 0) | (masks_b[rb] ? 2 : 0);
            }
        }
        body(254, e2A, mkA);

        // ---- final single step s=511 vs resident E, then denominator
        LGKM0();
        float u0, u1;
        matvec96(EB, ST, jj, u0, u1);
        const float2 e5 = *(const float2*)(em_b + (size_t)511 * NC + 2 * jj);
        if (masks_b[511]) { u0 *= __expf(e5.x); u1 *= __expf(e5.y); }
        else { u0 = (float)ST[2 * jj]; u1 = (float)ST[2 * jj + 1]; }
        const float2 en = *(const float2*)(endT + 2 * jj);
        const float dvl = (l < 48) ? (u0 * __expf(en.x) + u1 * __expf(en.y)) : 0.f;
        const float dv = wave_sum_all(dvl);
        if (l == 0)
            atomicAdd(out, -(M0 + (float)sk * LN2 + __logf(dv)) * (1.0f / (float)BATCH));
    } else {
        // ===================== producers =====================
        const int lidx = l & 15;
        const int g    = l >> 4;
        const int nt0  = 2 * (w - 1);    // this wave's two 16-col tiles

        // A = E (rows i), B = E (cols j); fixed register fragments
        half8 Ea[6][3];
        #pragma unroll
        for (int r = 0; r < 6; ++r)
            #pragma unroll
            for (int c = 0; c < 3; ++c) {
                half8 v;
                #pragma unroll
                for (int e = 0; e < 8; ++e)
                    v[e] = (__fp16)__expf(trans[(16 * r + lidx) * NC + 32 * c + 8 * g + e]);
                Ea[r][c] = v;
            }
        half8 Eb[3][2];
        #pragma unroll
        for (int c = 0; c < 3; ++c)
            #pragma unroll
            for (int ntL = 0; ntL < 2; ++ntL) {
                half8 v;
                #pragma unroll
                for (int e = 0; e < 8; ++e)
                    v[e] = (__fp16)__expf(trans[(32 * c + 8 * g + e) * NC + 16 * (nt0 + ntL) + lidx]);
                Eb[c][ntL] = v;
            }
        // write resident E (col-major, stride CSTR)
        #pragma unroll
        for (int ntL = 0; ntL < 2; ++ntL)
            #pragma unroll
            for (int c = 0; c < 3; ++c)
                *(uint4v*)(EB + (16 * (nt0 + ntL) + lidx) * CSTR + 32 * c + 8 * g) =
                    __builtin_bit_cast(uint4v, Eb[c][ntL]);

        auto build = [&](int bsel, const PF& pf) {
            half8 d0 = exp8(pf.a0, pf.a1);
            half8 d1 = exp8(pf.b0, pf.b1);
            half8 d2 = exp8(pf.c0, pf.c1);
            half8 bw[3][2];
            #pragma unroll
            for (int ntL = 0; ntL < 2; ++ntL) {
                bw[0][ntL] = Eb[0][ntL] * d0;
                bw[1][ntL] = Eb[1][ntL] * d1;
                bw[2][ntL] = Eb[2][ntL] * d2;
            }
            __fp16* dst = &GB[bsel][0];
            #pragma unroll
            for (int ntL = 0; ntL < 2; ++ntL) {
                #pragma unroll
                for (int r = 0; r < 6; ++r) {
                    const f32x4 z = {0.f, 0.f, 0.f, 0.f};
                    f32x4 acc = __builtin_amdgcn_mfma_f32_16x16x32_f16(Ea[r][0], bw[0][ntL], z, 0, 0, 0);
                    acc = __builtin_amdgcn_mfma_f32_16x16x32_f16(Ea[r][1], bw[1][ntL], acc, 0, 0, 0);
                    acc = __builtin_amdgcn_mfma_f32_16x16x32_f16(Ea[r][2], bw[2][ntL], acc, 0, 0, 0);
                    uint2v wv;
                    wv.x = bcu(__builtin_amdgcn_cvt_pkrtz(acc[0], acc[1]));
                    wv.y = bcu(__builtin_amdgcn_cvt_pkrtz(acc[2], acc[3]));
                    *(uint2v*)(dst + (16 * (nt0 + ntL) + lidx) * CSTR + 16 * r + 4 * g) = wv;
                }
            }
        };

        // prologue: G0 (uses em[1]); prefetch em[3], em[5]
        {
            const PF p0 = ld6(em_b, 1, g);
            build(0, p0);
        }
        PF r0 = ld6(em_b, 3, g);
        PF r1 = ld6(em_b, 5, g);

        #pragma unroll 1
        for (int t = 0; t < 254; t += 2) {
            BARRIER();
            build(1, r0);                                    // G[t+1] -> buf1
            { const int rr = 2 * t + 7; r0 = ld6(em_b, rr > 511 ? 511 : rr, g); }
            BARRIER();
            build(0, r1);                                    // G[t+2] -> buf0
            { const int rr = 2 * t + 9; r1 = ld6(em_b, rr > 511 ? 511 : rr, g); }
        }
        BARRIER();   // matches consumer body(254)

        // ---- numerator on wave 1 (tag-path gather for this chain)
        if (w == 1) {
            const int* tb = tags + (size_t)b * SEQ;
            float nsum = 0.f, msum = 0.f;
            #pragma unroll
            for (int kk = 0; kk < 8; ++kk) {
                const int s  = l + 64 * kk;
                const int tg = tb[s];
                const int mk = masks_b[s];
                msum += mk ? 1.f : 0.f;
                if (s == 0) {
                    nsum += startT[tg] + em_b[tg];
                } else if (mk) {
                    nsum += trans[tb[s - 1] * NC + tg] + em_b[(size_t)s * NC + tg];
                }
            }
            nsum = wave_sum_all(nsum);
            msum = wave_sum_all(msum);
            if (l == 0) {
                const int cnt  = (int)msum;
                const int last = tb[cnt - 1];
                atomicAdd(out, (nsum + endT[last]) * (1.0f / (float)BATCH));
            }
        }
    }
}

extern "C" void kernel_launch(void* const* d_in, const int* in_sizes, int n_in,
                              void* d_out, int out_size, void* d_ws, size_t ws_size,
                              hipStream_t stream) {
    const float* em     = (const float*)d_in[0];
    const int*   tags   = (const int*)  d_in[1];
    const int*   masks  = (const int*)  d_in[2];
    const float* startT = (const float*)d_in[3];
    const float* endT   = (const float*)d_in[4];
    const float* trans  = (const float*)d_in[5];
    float* out = (float*)d_out;

    (void)hipMemsetAsync(out, 0, sizeof(float), stream);
    crf_pair_kernel<<<BATCH, NTHR, 0, stream>>>(em, tags, masks, startT, endT, trans, out);
}